// Round 10
// baseline (426.121 us; speedup 1.0000x reference)
//
#include <hip/hip_runtime.h>

typedef _Float16 half8 __attribute__((ext_vector_type(8)));
typedef _Float16 half4v __attribute__((ext_vector_type(4)));
typedef float f32x4 __attribute__((ext_vector_type(4)));

#define EMB 1280
#define NHD 20
#define HDM 64
#define SEQ 1500
#define MTOT 6000
#define MPAD 6144
#define TPAD 1536
#define WSZ (1280 * 1280)
// 0.125 (head-dim scaling) * log2(e): attention runs in exp2 domain
#define QSCALE 0.18033688011112042f

__device__ __forceinline__ void gload_lds16(const void* g, void* l) {
  __builtin_amdgcn_global_load_lds(
      (const __attribute__((address_space(1))) void*)g,
      (__attribute__((address_space(3))) void*)l, 16, 0, 0);
}

// ---------------- f32 -> f16 converts ----------------

__global__ __launch_bounds__(256) void cvt_kernel(const float* __restrict__ s,
                                                  _Float16* __restrict__ d, int n8) {
  int i = blockIdx.x * 256 + threadIdx.x;
  if (i >= n8) return;
  const float4* sp = (const float4*)s + (size_t)i * 2;
  float4 a = sp[0], b = sp[1];
  half8 h;
  h[0] = (_Float16)a.x; h[1] = (_Float16)a.y; h[2] = (_Float16)a.z; h[3] = (_Float16)a.w;
  h[4] = (_Float16)b.x; h[5] = (_Float16)b.y; h[6] = (_Float16)b.z; h[7] = (_Float16)b.w;
  *((half8*)d + i) = h;
}

__global__ __launch_bounds__(256) void cvt4_kernel(const float* __restrict__ w0,
                                                   const float* __restrict__ w1,
                                                   const float* __restrict__ w2,
                                                   const float* __restrict__ w3,
                                                   _Float16* __restrict__ d) {
  const float* srcs[4] = {w0, w1, w2, w3};
  const float* s = srcs[blockIdx.y];
  int i = blockIdx.x * 256 + threadIdx.x;  // < WSZ/8
  const float4* sp = (const float4*)s + (size_t)i * 2;
  float4 a = sp[0], b = sp[1];
  half8 h;
  h[0] = (_Float16)a.x; h[1] = (_Float16)a.y; h[2] = (_Float16)a.z; h[3] = (_Float16)a.w;
  h[4] = (_Float16)b.x; h[5] = (_Float16)b.y; h[6] = (_Float16)b.z; h[7] = (_Float16)b.w;
  *((half8*)d + (size_t)blockIdx.y * (WSZ / 8) + i) = h;
}

// ---------------- GEMM: out[m][n] = sum_k A[m][k] * W[n][k]  (both K-major) ----
// mode 0: q = (acc+bq)*QSCALE -> f16 [MPAD][EMB]   (exp2-domain fold)
// mode 1: k = acc             -> f16 [MPAD][EMB]
// mode 2: v = acc+bv          -> f16 transposed [4][EMB][TPAD]
// mode 3: out = acc+bo        -> f32 [6000][EMB] (guarded)

__global__ __launch_bounds__(256) void gemm_kernel(
    const _Float16* __restrict__ A, const _Float16* __restrict__ Wb,
    const float* __restrict__ bq, const float* __restrict__ bv,
    const float* __restrict__ bo, _Float16* __restrict__ qh,
    _Float16* __restrict__ kh, _Float16* __restrict__ vth,
    float* __restrict__ fout, int mode_base) {
  __shared__ _Float16 As[2][128][32];
  __shared__ _Float16 Bs[2][128][32];
  const int tid = threadIdx.x;
  const int w = tid >> 6, l = tid & 63, lr = l & 15, lg = l >> 4;
  const int wr = w >> 1, wc = w & 1;
  const int rowBase = blockIdx.y * 128;
  const int colBase = blockIdx.x * 128;
  const int mode = mode_base + blockIdx.z;
  const _Float16* Bt = Wb + (size_t)blockIdx.z * WSZ;

  f32x4 acc[4][4] = {};
  const int K = EMB, NT = EMB / 32;

  auto stage = [&](int buf, int t0) {
    const int k0 = t0 * 32;
#pragma unroll
    for (int i = 0; i < 2; ++i) {
      int e = tid * 8 + i * 2048;
      int r = e >> 5, c = e & 31;
      gload_lds16(A + (size_t)(rowBase + r) * K + k0 + c, &As[buf][r][c]);
      gload_lds16(Bt + (size_t)(colBase + r) * K + k0 + c, &Bs[buf][r][c]);
    }
  };

  stage(0, 0);
  __syncthreads();
  int cur = 0;
  for (int t = 0; t < NT; ++t) {
    if (t + 1 < NT) stage(cur ^ 1, t + 1);
    half8 aF[4], bF[4];
#pragma unroll
    for (int mi = 0; mi < 4; ++mi)
      aF[mi] = *(const half8*)&As[cur][wr * 64 + mi * 16 + lr][lg * 8];
#pragma unroll
    for (int ni = 0; ni < 4; ++ni)
      bF[ni] = *(const half8*)&Bs[cur][wc * 64 + ni * 16 + lr][lg * 8];
#pragma unroll
    for (int mi = 0; mi < 4; ++mi)
#pragma unroll
      for (int ni = 0; ni < 4; ++ni)
        acc[mi][ni] = __builtin_amdgcn_mfma_f32_16x16x32_f16(aF[mi], bF[ni],
                                                             acc[mi][ni], 0, 0, 0);
    __syncthreads();
    cur ^= 1;
  }

#pragma unroll
  for (int ni = 0; ni < 4; ++ni) {
    const int col = colBase + wc * 64 + ni * 16 + lr;
    float bias = 0.f;
    if (mode == 0) bias = bq[col];
    else if (mode == 2) bias = bv[col];
    else if (mode == 3) bias = bo[col];
#pragma unroll
    for (int mi = 0; mi < 4; ++mi) {
      const int row0 = rowBase + wr * 64 + mi * 16 + lg * 4;
      if (mode == 0) {
#pragma unroll
        for (int j = 0; j < 4; ++j)
          qh[(size_t)(row0 + j) * EMB + col] =
              (_Float16)((acc[mi][ni][j] + bias) * QSCALE);
      } else if (mode == 1) {
#pragma unroll
        for (int j = 0; j < 4; ++j)
          kh[(size_t)(row0 + j) * EMB + col] = (_Float16)acc[mi][ni][j];
      } else if (mode == 2) {
        if (row0 < MTOT) {  // 4-row group never straddles batch (1500 % 4 == 0)
          int b = row0 / SEQ;
          int tt = row0 - b * SEQ;
          half4v hv;
          hv[0] = (_Float16)(acc[mi][ni][0] + bias);
          hv[1] = (_Float16)(acc[mi][ni][1] + bias);
          hv[2] = (_Float16)(acc[mi][ni][2] + bias);
          hv[3] = (_Float16)(acc[mi][ni][3] + bias);
          *(half4v*)(vth + ((size_t)b * EMB + col) * TPAD + tt) = hv;
        }
      } else {
#pragma unroll
        for (int j = 0; j < 4; ++j)
          if (row0 + j < MTOT)
            fout[(size_t)(row0 + j) * EMB + col] = acc[mi][ni][j] + bias;
      }
    }
  }
}

// ---------------- flash attention ----------------
// grid: (24 q-tiles, 80 b*h). 4 waves; wave owns 16 q-rows. KVBLK=64.
// rev2: exp2-domain softmax, defer-max THR=8, double-buffered K/V with raw
// s_barrier + counted vmcnt(4) (next tile's 4 gload_lds stay in flight),
// setprio around MFMA clusters.

__global__ __launch_bounds__(256) void attn_kernel(const _Float16* __restrict__ q,
                                                   const _Float16* __restrict__ k,
                                                   const _Float16* __restrict__ vt,
                                                   _Float16* __restrict__ o) {
  __shared__ _Float16 Ks[2][64][64];
  __shared__ _Float16 Vs[2][64][64];
  __shared__ _Float16 Ps[4][16][72];  // +8 pad: breaks 16-way conflict on P reads

  const int qt = blockIdx.x;
  const int bh = blockIdx.y;
  const int b = bh / NHD, h = bh % NHD;
  const int tid = threadIdx.x;
  const int w = tid >> 6, l = tid & 63, lr = l & 15, lg = l >> 4;

  const int q0 = qt * 64;
  const int qrow = q0 + w * 16 + lr;  // may exceed SEQ: in-bounds of MPAD, not stored
  const _Float16* qp = q + (size_t)(b * SEQ + qrow) * EMB + h * HDM;
  half8 aq0 = *(const half8*)(qp + lg * 8);
  half8 aq1 = *(const half8*)(qp + 32 + lg * 8);

  float m_r[4], l_r[4];
  f32x4 accO[4];
#pragma unroll
  for (int j = 0; j < 4; ++j) { m_r[j] = -1e30f; l_r[j] = 0.f; }
#pragma unroll
  for (int nf = 0; nf < 4; ++nf) {
    accO[nf][0] = 0.f; accO[nf][1] = 0.f; accO[nf][2] = 0.f; accO[nf][3] = 0.f;
  }

  const char* kBase = (const char*)(k + (size_t)b * SEQ * EMB + h * HDM);
  const char* vBase = (const char*)(vt + ((size_t)b * EMB + h * HDM) * TPAD);

  // source pre-swizzled (gload_lds dest must stay linear); read back with same XOR
  auto stage = [&](int buf, int kt) {
    const int kv0 = kt * 64;
#pragma unroll
    for (int i = 0; i < 2; ++i) {
      int o4 = tid * 16 + i * 4096;
      int r = o4 >> 7;
      int inner = o4 & 127;
      int srcoff = inner ^ ((r & 7) << 4);
      gload_lds16(kBase + (size_t)(kv0 + r) * (EMB * 2) + srcoff,
                  (char*)&Ks[buf][0][0] + o4);
      gload_lds16(vBase + (size_t)r * (TPAD * 2) + (size_t)kv0 * 2 + srcoff,
                  (char*)&Vs[buf][0][0] + o4);
    }
  };

  stage(0, 0);  // 4 loads in flight

  for (int kt = 0; kt < 24; ++kt) {
    const int cur = kt & 1;
    const int kv0 = kt * 64;
    // all waves done reading buf[cur^1] (prev iter) before restaging it
    __builtin_amdgcn_s_barrier();
    if (kt + 1 < 24) {
      stage(cur ^ 1, kt + 1);
      asm volatile("s_waitcnt vmcnt(4)" ::: "memory");  // cur's 4 loads landed; next 4 in flight
    } else {
      asm volatile("s_waitcnt vmcnt(0)" ::: "memory");
    }
    __builtin_amdgcn_s_barrier();  // every wave's cur loads landed
    asm volatile("" ::: "memory");

    // S = Q K^T  (C-layout: q-row = lg*4+j; kv col = nf*16+lr), log2 domain
    f32x4 s[4];
    __builtin_amdgcn_s_setprio(1);
#pragma unroll
    for (int nf = 0; nf < 4; ++nf) {
      int krow = nf * 16 + lr;
      const char* kb = (const char*)&Ks[cur][0][0] + krow * 128;
      int sw = (krow & 7) << 4;
      half8 bk0 = *(const half8*)(kb + ((lg * 16) ^ sw));
      half8 bk1 = *(const half8*)(kb + ((64 + lg * 16) ^ sw));
      f32x4 t = {0.f, 0.f, 0.f, 0.f};
      t = __builtin_amdgcn_mfma_f32_16x16x32_f16(aq0, bk0, t, 0, 0, 0);
      t = __builtin_amdgcn_mfma_f32_16x16x32_f16(aq1, bk1, t, 0, 0, 0);
      if (kv0 + krow >= SEQ) { t[0] = -1e30f; t[1] = -1e30f; t[2] = -1e30f; t[3] = -1e30f; }
      s[nf] = t;
    }
    __builtin_amdgcn_s_setprio(0);

    // tile row-max (reduce across the 16-lane lr group)
    float pmax[4];
#pragma unroll
    for (int j = 0; j < 4; ++j) {
      float mx = fmaxf(fmaxf(s[0][j], s[1][j]), fmaxf(s[2][j], s[3][j]));
      mx = fmaxf(mx, __shfl_xor(mx, 1));
      mx = fmaxf(mx, __shfl_xor(mx, 2));
      mx = fmaxf(mx, __shfl_xor(mx, 4));
      mx = fmaxf(mx, __shfl_xor(mx, 8));
      pmax[j] = mx;
    }
    // defer-max: skip O/l rescale while max growth < 8 (P bounded by 2^8, f16-safe)
    float dm = fmaxf(fmaxf(pmax[0] - m_r[0], pmax[1] - m_r[1]),
                     fmaxf(pmax[2] - m_r[2], pmax[3] - m_r[3]));
    if (!__all(dm <= 8.0f)) {
#pragma unroll
      for (int j = 0; j < 4; ++j) {
        float mnew = fmaxf(m_r[j], pmax[j]);
        float corr = exp2f(m_r[j] - mnew);
        m_r[j] = mnew;
        l_r[j] *= corr;
#pragma unroll
        for (int nf = 0; nf < 4; ++nf) accO[nf][j] *= corr;
      }
    }

    float p[4][4];
#pragma unroll
    for (int j = 0; j < 4; ++j) {
      float rs = 0.f;
#pragma unroll
      for (int nf = 0; nf < 4; ++nf) {
        float e = exp2f(s[nf][j] - m_r[j]);
        p[nf][j] = e;
        rs += e;
      }
      rs += __shfl_xor(rs, 1);
      rs += __shfl_xor(rs, 2);
      rs += __shfl_xor(rs, 4);
      rs += __shfl_xor(rs, 8);
      l_r[j] += rs;
    }

    // P -> LDS (per-wave region), re-read in A-fragment layout
#pragma unroll
    for (int j = 0; j < 4; ++j)
#pragma unroll
      for (int nf = 0; nf < 4; ++nf)
        Ps[w][lg * 4 + j][nf * 16 + lr] = (_Float16)p[nf][j];

    half8 ap0 = *(const half8*)&Ps[w][lr][lg * 8];
    half8 ap1 = *(const half8*)&Ps[w][lr][32 + lg * 8];
    __builtin_amdgcn_s_setprio(1);
#pragma unroll
    for (int nf = 0; nf < 4; ++nf) {
      int vrow = nf * 16 + lr;
      const char* vb = (const char*)&Vs[cur][0][0] + vrow * 128;
      int sw = (vrow & 7) << 4;
      half8 bv0 = *(const half8*)(vb + ((lg * 16) ^ sw));
      half8 bv1 = *(const half8*)(vb + ((64 + lg * 16) ^ sw));
      accO[nf] = __builtin_amdgcn_mfma_f32_16x16x32_f16(ap0, bv0, accO[nf], 0, 0, 0);
      accO[nf] = __builtin_amdgcn_mfma_f32_16x16x32_f16(ap1, bv1, accO[nf], 0, 0, 0);
    }
    __builtin_amdgcn_s_setprio(0);
  }

#pragma unroll
  for (int j = 0; j < 4; ++j) {
    int tt = q0 + w * 16 + lg * 4 + j;
    if (tt < SEQ) {
      float inv = 1.f / l_r[j];
      _Float16* op = o + (size_t)(b * SEQ + tt) * EMB + h * HDM;
#pragma unroll
      for (int nf = 0; nf < 4; ++nf)
        op[nf * 16 + lr] = (_Float16)(accO[nf][j] * inv);
    }
  }
}

// ---------------- launcher ----------------

extern "C" void kernel_launch(void* const* d_in, const int* in_sizes, int n_in,
                              void* d_out, int out_size, void* d_ws, size_t ws_size,
                              hipStream_t stream) {
  const float* X = (const float*)d_in[0];
  const float* Wq = (const float*)d_in[1];
  const float* bq = (const float*)d_in[2];
  const float* Wk = (const float*)d_in[3];
  const float* Wv = (const float*)d_in[4];
  const float* bv = (const float*)d_in[5];
  const float* Wo = (const float*)d_in[6];
  const float* bo = (const float*)d_in[7];
  float* out = (float*)d_out;

  // workspace layout (all f16): Xh | Wh[4] | qh | kh | vth | aoh  = ~87.5 MB
  _Float16* Xh = (_Float16*)d_ws;
  _Float16* Wh = Xh + (size_t)MPAD * EMB;
  _Float16* qh = Wh + (size_t)4 * WSZ;
  _Float16* kh = qh + (size_t)MPAD * EMB;
  _Float16* vth = kh + (size_t)MPAD * EMB;  // 4*EMB*TPAD == MPAD*EMB
  _Float16* aoh = vth + (size_t)MPAD * EMB;

  cvt_kernel<<<dim3((MTOT * EMB / 8 + 255) / 256), 256, 0, stream>>>(X, Xh,
                                                                     MTOT * EMB / 8);
  cvt4_kernel<<<dim3(WSZ / 8 / 256, 4), 256, 0, stream>>>(Wq, Wk, Wv, Wo, Wh);

  // fused QKV projection: grid.z selects {q,k,v}
  gemm_kernel<<<dim3(10, 48, 3), 256, 0, stream>>>(Xh, Wh, bq, bv, bo, qh, kh, vth,
                                                   out, 0);
  attn_kernel<<<dim3(24, 80), 256, 0, stream>>>(qh, kh, vth, aoh);
  // output projection
  gemm_kernel<<<dim3(10, 48, 1), 256, 0, stream>>>(aoh, Wh + (size_t)3 * WSZ, bq, bv,
                                                   bo, qh, kh, vth, out, 3);
}

// Round 11
// 416.662 us; speedup vs baseline: 1.0227x; 1.0227x over previous
//
#include <hip/hip_runtime.h>

typedef _Float16 half8 __attribute__((ext_vector_type(8)));
typedef _Float16 half4v __attribute__((ext_vector_type(4)));
typedef float f32x4 __attribute__((ext_vector_type(4)));

#define EMB 1280
#define NHD 20
#define HDM 64
#define SEQ 1500
#define MTOT 6000
#define MPAD 6144
#define TPAD 1536
#define WSZ (1280 * 1280)
// 0.125 (head-dim scaling) * log2(e): attention runs in exp2 domain
#define QSCALE 0.18033688011112042f

__device__ __forceinline__ void gload_lds16(const void* g, void* l) {
  __builtin_amdgcn_global_load_lds(
      (const __attribute__((address_space(1))) void*)g,
      (__attribute__((address_space(3))) void*)l, 16, 0, 0);
}

// ---------------- f32 -> f16 converts ----------------

__global__ __launch_bounds__(256) void cvt_kernel(const float* __restrict__ s,
                                                  _Float16* __restrict__ d, int n8) {
  int i = blockIdx.x * 256 + threadIdx.x;
  if (i >= n8) return;
  const float4* sp = (const float4*)s + (size_t)i * 2;
  float4 a = sp[0], b = sp[1];
  half8 h;
  h[0] = (_Float16)a.x; h[1] = (_Float16)a.y; h[2] = (_Float16)a.z; h[3] = (_Float16)a.w;
  h[4] = (_Float16)b.x; h[5] = (_Float16)b.y; h[6] = (_Float16)b.z; h[7] = (_Float16)b.w;
  *((half8*)d + i) = h;
}

__global__ __launch_bounds__(256) void cvt4_kernel(const float* __restrict__ w0,
                                                   const float* __restrict__ w1,
                                                   const float* __restrict__ w2,
                                                   const float* __restrict__ w3,
                                                   _Float16* __restrict__ d) {
  const float* srcs[4] = {w0, w1, w2, w3};
  const float* s = srcs[blockIdx.y];
  int i = blockIdx.x * 256 + threadIdx.x;  // < WSZ/8
  const float4* sp = (const float4*)s + (size_t)i * 2;
  float4 a = sp[0], b = sp[1];
  half8 h;
  h[0] = (_Float16)a.x; h[1] = (_Float16)a.y; h[2] = (_Float16)a.z; h[3] = (_Float16)a.w;
  h[4] = (_Float16)b.x; h[5] = (_Float16)b.y; h[6] = (_Float16)b.z; h[7] = (_Float16)b.w;
  *((half8*)d + (size_t)blockIdx.y * (WSZ / 8) + i) = h;
}

// ---------------- GEMM: out[m][n] = sum_k A[m][k] * W[n][k]  (both K-major) ----
// mode 0: q = (acc+bq)*QSCALE -> f16 [MPAD][EMB]   (exp2-domain fold)
// mode 1: k = acc             -> f16 [MPAD][EMB]
// mode 2: v = acc+bv          -> f16 transposed [4][EMB][TPAD]
// mode 3: out = acc+bo        -> f32 [6000][EMB] (guarded)

__global__ __launch_bounds__(256) void gemm_kernel(
    const _Float16* __restrict__ A, const _Float16* __restrict__ Wb,
    const float* __restrict__ bq, const float* __restrict__ bv,
    const float* __restrict__ bo, _Float16* __restrict__ qh,
    _Float16* __restrict__ kh, _Float16* __restrict__ vth,
    float* __restrict__ fout, int mode_base) {
  __shared__ _Float16 As[2][128][32];
  __shared__ _Float16 Bs[2][128][32];
  const int tid = threadIdx.x;
  const int w = tid >> 6, l = tid & 63, lr = l & 15, lg = l >> 4;
  const int wr = w >> 1, wc = w & 1;
  const int rowBase = blockIdx.y * 128;
  const int colBase = blockIdx.x * 128;
  const int mode = mode_base + blockIdx.z;
  const _Float16* Bt = Wb + (size_t)blockIdx.z * WSZ;

  f32x4 acc[4][4] = {};
  const int K = EMB, NT = EMB / 32;

  auto stage = [&](int buf, int t0) {
    const int k0 = t0 * 32;
#pragma unroll
    for (int i = 0; i < 2; ++i) {
      int e = tid * 8 + i * 2048;
      int r = e >> 5, c = e & 31;
      gload_lds16(A + (size_t)(rowBase + r) * K + k0 + c, &As[buf][r][c]);
      gload_lds16(Bt + (size_t)(colBase + r) * K + k0 + c, &Bs[buf][r][c]);
    }
  };

  stage(0, 0);
  __syncthreads();
  int cur = 0;
  for (int t = 0; t < NT; ++t) {
    if (t + 1 < NT) stage(cur ^ 1, t + 1);
    half8 aF[4], bF[4];
#pragma unroll
    for (int mi = 0; mi < 4; ++mi)
      aF[mi] = *(const half8*)&As[cur][wr * 64 + mi * 16 + lr][lg * 8];
#pragma unroll
    for (int ni = 0; ni < 4; ++ni)
      bF[ni] = *(const half8*)&Bs[cur][wc * 64 + ni * 16 + lr][lg * 8];
#pragma unroll
    for (int mi = 0; mi < 4; ++mi)
#pragma unroll
      for (int ni = 0; ni < 4; ++ni)
        acc[mi][ni] = __builtin_amdgcn_mfma_f32_16x16x32_f16(aF[mi], bF[ni],
                                                             acc[mi][ni], 0, 0, 0);
    __syncthreads();
    cur ^= 1;
  }

#pragma unroll
  for (int ni = 0; ni < 4; ++ni) {
    const int col = colBase + wc * 64 + ni * 16 + lr;
    float bias = 0.f;
    if (mode == 0) bias = bq[col];
    else if (mode == 2) bias = bv[col];
    else if (mode == 3) bias = bo[col];
#pragma unroll
    for (int mi = 0; mi < 4; ++mi) {
      const int row0 = rowBase + wr * 64 + mi * 16 + lg * 4;
      if (mode == 0) {
#pragma unroll
        for (int j = 0; j < 4; ++j)
          qh[(size_t)(row0 + j) * EMB + col] =
              (_Float16)((acc[mi][ni][j] + bias) * QSCALE);
      } else if (mode == 1) {
#pragma unroll
        for (int j = 0; j < 4; ++j)
          kh[(size_t)(row0 + j) * EMB + col] = (_Float16)acc[mi][ni][j];
      } else if (mode == 2) {
        if (row0 < MTOT) {  // 4-row group never straddles batch (1500 % 4 == 0)
          int b = row0 / SEQ;
          int tt = row0 - b * SEQ;
          half4v hv;
          hv[0] = (_Float16)(acc[mi][ni][0] + bias);
          hv[1] = (_Float16)(acc[mi][ni][1] + bias);
          hv[2] = (_Float16)(acc[mi][ni][2] + bias);
          hv[3] = (_Float16)(acc[mi][ni][3] + bias);
          *(half4v*)(vth + ((size_t)b * EMB + col) * TPAD + tt) = hv;
        }
      } else {
#pragma unroll
        for (int j = 0; j < 4; ++j)
          if (row0 + j < MTOT)
            fout[(size_t)(row0 + j) * EMB + col] = acc[mi][ni][j] + bias;
      }
    }
  }
}

// ---------------- flash attention ----------------
// grid: (24 q-tiles, 80 b*h). 4 waves; wave owns 16 q-rows. KVBLK=64.
// rev3 = round-9 structure (single-buffer K/V, 25.6KB LDS -> 6 blocks/CU;
// inter-block TLP hides staging) + exp2-domain softmax + defer-max THR=8.
// (rev2's dbuf halved residency 6->3 blocks/CU: 181 -> 202 us. Reverted.)

__global__ __launch_bounds__(256) void attn_kernel(const _Float16* __restrict__ q,
                                                   const _Float16* __restrict__ k,
                                                   const _Float16* __restrict__ vt,
                                                   _Float16* __restrict__ o) {
  __shared__ _Float16 Ks[64][64];
  __shared__ _Float16 Vs[64][64];
  __shared__ _Float16 Ps[4][16][72];  // +8 pad: breaks 16-way conflict on P reads

  const int qt = blockIdx.x;
  const int bh = blockIdx.y;
  const int b = bh / NHD, h = bh % NHD;
  const int tid = threadIdx.x;
  const int w = tid >> 6, l = tid & 63, lr = l & 15, lg = l >> 4;

  const int q0 = qt * 64;
  const int qrow = q0 + w * 16 + lr;  // may exceed SEQ: in-bounds of MPAD, not stored
  const _Float16* qp = q + (size_t)(b * SEQ + qrow) * EMB + h * HDM;
  half8 aq0 = *(const half8*)(qp + lg * 8);
  half8 aq1 = *(const half8*)(qp + 32 + lg * 8);

  float m_r[4], l_r[4];
  f32x4 accO[4];
#pragma unroll
  for (int j = 0; j < 4; ++j) { m_r[j] = -1e30f; l_r[j] = 0.f; }
#pragma unroll
  for (int nf = 0; nf < 4; ++nf) {
    accO[nf][0] = 0.f; accO[nf][1] = 0.f; accO[nf][2] = 0.f; accO[nf][3] = 0.f;
  }

  const char* kBase = (const char*)(k + (size_t)b * SEQ * EMB + h * HDM);
  const char* vBase = (const char*)(vt + ((size_t)b * EMB + h * HDM) * TPAD);

  for (int kt = 0; kt < 24; ++kt) {
    const int kv0 = kt * 64;
    __syncthreads();  // prev tile's LDS reads complete before overwrite
#pragma unroll
    for (int i = 0; i < 2; ++i) {
      int o4 = tid * 16 + i * 4096;
      int r = o4 >> 7;
      int inner = o4 & 127;
      int srcoff = inner ^ ((r & 7) << 4);
      gload_lds16(kBase + (size_t)(kv0 + r) * (EMB * 2) + srcoff,
                  (char*)&Ks[0][0] + o4);
      gload_lds16(vBase + (size_t)r * (TPAD * 2) + (size_t)kv0 * 2 + srcoff,
                  (char*)&Vs[0][0] + o4);
    }
    __syncthreads();  // drains vmcnt (compiler emits vmcnt(0) before s_barrier)

    // S = Q K^T  (C-layout: q-row = lg*4+j; kv col = nf*16+lr), log2 domain
    f32x4 s[4];
#pragma unroll
    for (int nf = 0; nf < 4; ++nf) {
      int krow = nf * 16 + lr;
      const char* kb = (const char*)&Ks[0][0] + krow * 128;
      int sw = (krow & 7) << 4;
      half8 bk0 = *(const half8*)(kb + ((lg * 16) ^ sw));
      half8 bk1 = *(const half8*)(kb + ((64 + lg * 16) ^ sw));
      f32x4 t = {0.f, 0.f, 0.f, 0.f};
      t = __builtin_amdgcn_mfma_f32_16x16x32_f16(aq0, bk0, t, 0, 0, 0);
      t = __builtin_amdgcn_mfma_f32_16x16x32_f16(aq1, bk1, t, 0, 0, 0);
      if (kv0 + krow >= SEQ) { t[0] = -1e30f; t[1] = -1e30f; t[2] = -1e30f; t[3] = -1e30f; }
      s[nf] = t;
    }

    // tile row-max (reduce across the 16-lane lr group)
    float pmax[4];
#pragma unroll
    for (int j = 0; j < 4; ++j) {
      float mx = fmaxf(fmaxf(s[0][j], s[1][j]), fmaxf(s[2][j], s[3][j]));
      mx = fmaxf(mx, __shfl_xor(mx, 1));
      mx = fmaxf(mx, __shfl_xor(mx, 2));
      mx = fmaxf(mx, __shfl_xor(mx, 4));
      mx = fmaxf(mx, __shfl_xor(mx, 8));
      pmax[j] = mx;
    }
    // defer-max: skip O/l rescale while max growth < 8 (P bounded by 2^8, f16-safe)
    float dm = fmaxf(fmaxf(pmax[0] - m_r[0], pmax[1] - m_r[1]),
                     fmaxf(pmax[2] - m_r[2], pmax[3] - m_r[3]));
    if (!__all(dm <= 8.0f)) {
#pragma unroll
      for (int j = 0; j < 4; ++j) {
        float mnew = fmaxf(m_r[j], pmax[j]);
        float corr = exp2f(m_r[j] - mnew);
        m_r[j] = mnew;
        l_r[j] *= corr;
#pragma unroll
        for (int nf = 0; nf < 4; ++nf) accO[nf][j] *= corr;
      }
    }

    float p[4][4];
#pragma unroll
    for (int j = 0; j < 4; ++j) {
      float rs = 0.f;
#pragma unroll
      for (int nf = 0; nf < 4; ++nf) {
        float e = exp2f(s[nf][j] - m_r[j]);
        p[nf][j] = e;
        rs += e;
      }
      rs += __shfl_xor(rs, 1);
      rs += __shfl_xor(rs, 2);
      rs += __shfl_xor(rs, 4);
      rs += __shfl_xor(rs, 8);
      l_r[j] += rs;
    }

    // P -> LDS (per-wave region), re-read in A-fragment layout
#pragma unroll
    for (int j = 0; j < 4; ++j)
#pragma unroll
      for (int nf = 0; nf < 4; ++nf)
        Ps[w][lg * 4 + j][nf * 16 + lr] = (_Float16)p[nf][j];

    half8 ap0 = *(const half8*)&Ps[w][lr][lg * 8];
    half8 ap1 = *(const half8*)&Ps[w][lr][32 + lg * 8];
#pragma unroll
    for (int nf = 0; nf < 4; ++nf) {
      int vrow = nf * 16 + lr;
      const char* vb = (const char*)&Vs[0][0] + vrow * 128;
      int sw = (vrow & 7) << 4;
      half8 bv0 = *(const half8*)(vb + ((lg * 16) ^ sw));
      half8 bv1 = *(const half8*)(vb + ((64 + lg * 16) ^ sw));
      accO[nf] = __builtin_amdgcn_mfma_f32_16x16x32_f16(ap0, bv0, accO[nf], 0, 0, 0);
      accO[nf] = __builtin_amdgcn_mfma_f32_16x16x32_f16(ap1, bv1, accO[nf], 0, 0, 0);
    }
  }

#pragma unroll
  for (int j = 0; j < 4; ++j) {
    int tt = q0 + w * 16 + lg * 4 + j;
    if (tt < SEQ) {
      float inv = 1.f / l_r[j];
      _Float16* op = o + (size_t)(b * SEQ + tt) * EMB + h * HDM;
#pragma unroll
      for (int nf = 0; nf < 4; ++nf)
        op[nf * 16 + lr] = (_Float16)(accO[nf][j] * inv);
    }
  }
}

// ---------------- launcher ----------------

extern "C" void kernel_launch(void* const* d_in, const int* in_sizes, int n_in,
                              void* d_out, int out_size, void* d_ws, size_t ws_size,
                              hipStream_t stream) {
  const float* X = (const float*)d_in[0];
  const float* Wq = (const float*)d_in[1];
  const float* bq = (const float*)d_in[2];
  const float* Wk = (const float*)d_in[3];
  const float* Wv = (const float*)d_in[4];
  const float* bv = (const float*)d_in[5];
  const float* Wo = (const float*)d_in[6];
  const float* bo = (const float*)d_in[7];
  float* out = (float*)d_out;

  // workspace layout (all f16): Xh | Wh[4] | qh | kh | vth | aoh  = ~87.5 MB
  _Float16* Xh = (_Float16*)d_ws;
  _Float16* Wh = Xh + (size_t)MPAD * EMB;
  _Float16* qh = Wh + (size_t)4 * WSZ;
  _Float16* kh = qh + (size_t)MPAD * EMB;
  _Float16* vth = kh + (size_t)MPAD * EMB;  // 4*EMB*TPAD == MPAD*EMB
  _Float16* aoh = vth + (size_t)MPAD * EMB;

  cvt_kernel<<<dim3((MTOT * EMB / 8 + 255) / 256), 256, 0, stream>>>(X, Xh,
                                                                     MTOT * EMB / 8);
  cvt4_kernel<<<dim3(WSZ / 8 / 256, 4), 256, 0, stream>>>(Wq, Wk, Wv, Wo, Wh);

  // fused QKV projection: grid.z selects {q,k,v}
  gemm_kernel<<<dim3(10, 48, 3), 256, 0, stream>>>(Xh, Wh, bq, bv, bo, qh, kh, vth,
                                                   out, 0);
  attn_kernel<<<dim3(24, 80), 256, 0, stream>>>(qh, kh, vth, aoh);
  // output projection
  gemm_kernel<<<dim3(10, 48, 1), 256, 0, stream>>>(aoh, Wh + (size_t)3 * WSZ, bq, bv,
                                                   bo, qh, kh, vth, out, 3);
}

// Round 12
// 405.483 us; speedup vs baseline: 1.0509x; 1.0276x over previous
//
#include <hip/hip_runtime.h>

typedef _Float16 half8 __attribute__((ext_vector_type(8)));
typedef _Float16 half4v __attribute__((ext_vector_type(4)));
typedef float f32x4 __attribute__((ext_vector_type(4)));

#define EMB 1280
#define NHD 20
#define HDM 64
#define SEQ 1500
#define MTOT 6000
#define MPAD 6144
#define TPAD 1536
#define WSZ (1280 * 1280)
// 0.125 (head-dim scaling) * log2(e): attention runs in exp2 domain
#define QSCALE 0.18033688011112042f

__device__ __forceinline__ void gload_lds16(const void* g, void* l) {
  __builtin_amdgcn_global_load_lds(
      (const __attribute__((address_space(1))) void*)g,
      (__attribute__((address_space(3))) void*)l, 16, 0, 0);
}

// native v_exp_f32 (exp2). libm exp2f w/o fast-math expands to ~10-inst
// range-handling sequence (r11 regression: VALUBusy 48.5->54.5).
__device__ __forceinline__ float exp2_fast(float x) {
  return __builtin_amdgcn_exp2f(x);
}

// ---------------- f32 -> f16 converts ----------------

__global__ __launch_bounds__(256) void cvt_kernel(const float* __restrict__ s,
                                                  _Float16* __restrict__ d, int n8) {
  int i = blockIdx.x * 256 + threadIdx.x;
  if (i >= n8) return;
  const float4* sp = (const float4*)s + (size_t)i * 2;
  float4 a = sp[0], b = sp[1];
  half8 h;
  h[0] = (_Float16)a.x; h[1] = (_Float16)a.y; h[2] = (_Float16)a.z; h[3] = (_Float16)a.w;
  h[4] = (_Float16)b.x; h[5] = (_Float16)b.y; h[6] = (_Float16)b.z; h[7] = (_Float16)b.w;
  *((half8*)d + i) = h;
}

__global__ __launch_bounds__(256) void cvt4_kernel(const float* __restrict__ w0,
                                                   const float* __restrict__ w1,
                                                   const float* __restrict__ w2,
                                                   const float* __restrict__ w3,
                                                   _Float16* __restrict__ d) {
  const float* srcs[4] = {w0, w1, w2, w3};
  const float* s = srcs[blockIdx.y];
  int i = blockIdx.x * 256 + threadIdx.x;  // < WSZ/8
  const float4* sp = (const float4*)s + (size_t)i * 2;
  float4 a = sp[0], b = sp[1];
  half8 h;
  h[0] = (_Float16)a.x; h[1] = (_Float16)a.y; h[2] = (_Float16)a.z; h[3] = (_Float16)a.w;
  h[4] = (_Float16)b.x; h[5] = (_Float16)b.y; h[6] = (_Float16)b.z; h[7] = (_Float16)b.w;
  *((half8*)d + (size_t)blockIdx.y * (WSZ / 8) + i) = h;
}

// ---------------- GEMM: out[m][n] = sum_k A[m][k] * W[n][k]  (both K-major) ----
// mode 0: q = (acc+bq)*QSCALE -> f16 [MPAD][EMB]   (exp2-domain fold)
// mode 1: k = acc             -> f16 [MPAD][EMB]
// mode 2: v = acc+bv          -> f16 transposed [4][EMB][TPAD]
// mode 3: out = acc+bo        -> f32 [6000][EMB] (guarded)

__global__ __launch_bounds__(256) void gemm_kernel(
    const _Float16* __restrict__ A, const _Float16* __restrict__ Wb,
    const float* __restrict__ bq, const float* __restrict__ bv,
    const float* __restrict__ bo, _Float16* __restrict__ qh,
    _Float16* __restrict__ kh, _Float16* __restrict__ vth,
    float* __restrict__ fout, int mode_base) {
  __shared__ _Float16 As[2][128][32];
  __shared__ _Float16 Bs[2][128][32];
  const int tid = threadIdx.x;
  const int w = tid >> 6, l = tid & 63, lr = l & 15, lg = l >> 4;
  const int wr = w >> 1, wc = w & 1;
  const int rowBase = blockIdx.y * 128;
  const int colBase = blockIdx.x * 128;
  const int mode = mode_base + blockIdx.z;
  const _Float16* Bt = Wb + (size_t)blockIdx.z * WSZ;

  f32x4 acc[4][4] = {};
  const int K = EMB, NT = EMB / 32;

  auto stage = [&](int buf, int t0) {
    const int k0 = t0 * 32;
#pragma unroll
    for (int i = 0; i < 2; ++i) {
      int e = tid * 8 + i * 2048;
      int r = e >> 5, c = e & 31;
      gload_lds16(A + (size_t)(rowBase + r) * K + k0 + c, &As[buf][r][c]);
      gload_lds16(Bt + (size_t)(colBase + r) * K + k0 + c, &Bs[buf][r][c]);
    }
  };

  stage(0, 0);
  __syncthreads();
  int cur = 0;
  for (int t = 0; t < NT; ++t) {
    if (t + 1 < NT) stage(cur ^ 1, t + 1);
    half8 aF[4], bF[4];
#pragma unroll
    for (int mi = 0; mi < 4; ++mi)
      aF[mi] = *(const half8*)&As[cur][wr * 64 + mi * 16 + lr][lg * 8];
#pragma unroll
    for (int ni = 0; ni < 4; ++ni)
      bF[ni] = *(const half8*)&Bs[cur][wc * 64 + ni * 16 + lr][lg * 8];
#pragma unroll
    for (int mi = 0; mi < 4; ++mi)
#pragma unroll
      for (int ni = 0; ni < 4; ++ni)
        acc[mi][ni] = __builtin_amdgcn_mfma_f32_16x16x32_f16(aF[mi], bF[ni],
                                                             acc[mi][ni], 0, 0, 0);
    __syncthreads();
    cur ^= 1;
  }

#pragma unroll
  for (int ni = 0; ni < 4; ++ni) {
    const int col = colBase + wc * 64 + ni * 16 + lr;
    float bias = 0.f;
    if (mode == 0) bias = bq[col];
    else if (mode == 2) bias = bv[col];
    else if (mode == 3) bias = bo[col];
#pragma unroll
    for (int mi = 0; mi < 4; ++mi) {
      const int row0 = rowBase + wr * 64 + mi * 16 + lg * 4;
      if (mode == 0) {
#pragma unroll
        for (int j = 0; j < 4; ++j)
          qh[(size_t)(row0 + j) * EMB + col] =
              (_Float16)((acc[mi][ni][j] + bias) * QSCALE);
      } else if (mode == 1) {
#pragma unroll
        for (int j = 0; j < 4; ++j)
          kh[(size_t)(row0 + j) * EMB + col] = (_Float16)acc[mi][ni][j];
      } else if (mode == 2) {
        if (row0 < MTOT) {  // 4-row group never straddles batch (1500 % 4 == 0)
          int b = row0 / SEQ;
          int tt = row0 - b * SEQ;
          half4v hv;
          hv[0] = (_Float16)(acc[mi][ni][0] + bias);
          hv[1] = (_Float16)(acc[mi][ni][1] + bias);
          hv[2] = (_Float16)(acc[mi][ni][2] + bias);
          hv[3] = (_Float16)(acc[mi][ni][3] + bias);
          *(half4v*)(vth + ((size_t)b * EMB + col) * TPAD + tt) = hv;
        }
      } else {
#pragma unroll
        for (int j = 0; j < 4; ++j)
          if (row0 + j < MTOT)
            fout[(size_t)(row0 + j) * EMB + col] = acc[mi][ni][j] + bias;
      }
    }
  }
}

// ---------------- flash attention ----------------
// grid: (24 q-tiles, 80 b*h). 4 waves; wave owns 16 q-rows. KVBLK=64.
// rev4 = rev3 structure (single-buffer K/V, 25.6KB LDS, 6 blocks/CU) with
// native v_exp_f32 softmax (exp2 domain, QSCALE fold) + defer-max THR=8.

__global__ __launch_bounds__(256) void attn_kernel(const _Float16* __restrict__ q,
                                                   const _Float16* __restrict__ k,
                                                   const _Float16* __restrict__ vt,
                                                   _Float16* __restrict__ o) {
  __shared__ _Float16 Ks[64][64];
  __shared__ _Float16 Vs[64][64];
  __shared__ _Float16 Ps[4][16][72];  // +8 pad: breaks 16-way conflict on P reads

  const int qt = blockIdx.x;
  const int bh = blockIdx.y;
  const int b = bh / NHD, h = bh % NHD;
  const int tid = threadIdx.x;
  const int w = tid >> 6, l = tid & 63, lr = l & 15, lg = l >> 4;

  const int q0 = qt * 64;
  const int qrow = q0 + w * 16 + lr;  // may exceed SEQ: in-bounds of MPAD, not stored
  const _Float16* qp = q + (size_t)(b * SEQ + qrow) * EMB + h * HDM;
  half8 aq0 = *(const half8*)(qp + lg * 8);
  half8 aq1 = *(const half8*)(qp + 32 + lg * 8);

  float m_r[4], l_r[4];
  f32x4 accO[4];
#pragma unroll
  for (int j = 0; j < 4; ++j) { m_r[j] = -1e30f; l_r[j] = 0.f; }
#pragma unroll
  for (int nf = 0; nf < 4; ++nf) {
    accO[nf][0] = 0.f; accO[nf][1] = 0.f; accO[nf][2] = 0.f; accO[nf][3] = 0.f;
  }

  const char* kBase = (const char*)(k + (size_t)b * SEQ * EMB + h * HDM);
  const char* vBase = (const char*)(vt + ((size_t)b * EMB + h * HDM) * TPAD);

  for (int kt = 0; kt < 24; ++kt) {
    const int kv0 = kt * 64;
    __syncthreads();  // prev tile's LDS reads complete before overwrite
#pragma unroll
    for (int i = 0; i < 2; ++i) {
      int o4 = tid * 16 + i * 4096;
      int r = o4 >> 7;
      int inner = o4 & 127;
      int srcoff = inner ^ ((r & 7) << 4);
      gload_lds16(kBase + (size_t)(kv0 + r) * (EMB * 2) + srcoff,
                  (char*)&Ks[0][0] + o4);
      gload_lds16(vBase + (size_t)r * (TPAD * 2) + (size_t)kv0 * 2 + srcoff,
                  (char*)&Vs[0][0] + o4);
    }
    __syncthreads();  // drains vmcnt (compiler emits vmcnt(0) before s_barrier)

    // S = Q K^T  (C-layout: q-row = lg*4+j; kv col = nf*16+lr), log2 domain
    f32x4 s[4];
#pragma unroll
    for (int nf = 0; nf < 4; ++nf) {
      int krow = nf * 16 + lr;
      const char* kb = (const char*)&Ks[0][0] + krow * 128;
      int sw = (krow & 7) << 4;
      half8 bk0 = *(const half8*)(kb + ((lg * 16) ^ sw));
      half8 bk1 = *(const half8*)(kb + ((64 + lg * 16) ^ sw));
      f32x4 t = {0.f, 0.f, 0.f, 0.f};
      t = __builtin_amdgcn_mfma_f32_16x16x32_f16(aq0, bk0, t, 0, 0, 0);
      t = __builtin_amdgcn_mfma_f32_16x16x32_f16(aq1, bk1, t, 0, 0, 0);
      if (kv0 + krow >= SEQ) { t[0] = -1e30f; t[1] = -1e30f; t[2] = -1e30f; t[3] = -1e30f; }
      s[nf] = t;
    }

    // tile row-max (reduce across the 16-lane lr group)
    float pmax[4];
#pragma unroll
    for (int j = 0; j < 4; ++j) {
      float mx = fmaxf(fmaxf(s[0][j], s[1][j]), fmaxf(s[2][j], s[3][j]));
      mx = fmaxf(mx, __shfl_xor(mx, 1));
      mx = fmaxf(mx, __shfl_xor(mx, 2));
      mx = fmaxf(mx, __shfl_xor(mx, 4));
      mx = fmaxf(mx, __shfl_xor(mx, 8));
      pmax[j] = mx;
    }
    // defer-max: skip O/l rescale while max growth < 8 (P bounded by 2^8, f16-safe)
    float dm = fmaxf(fmaxf(pmax[0] - m_r[0], pmax[1] - m_r[1]),
                     fmaxf(pmax[2] - m_r[2], pmax[3] - m_r[3]));
    if (!__all(dm <= 8.0f)) {
#pragma unroll
      for (int j = 0; j < 4; ++j) {
        float mnew = fmaxf(m_r[j], pmax[j]);
        float corr = exp2_fast(m_r[j] - mnew);
        m_r[j] = mnew;
        l_r[j] *= corr;
#pragma unroll
        for (int nf = 0; nf < 4; ++nf) accO[nf][j] *= corr;
      }
    }

    float p[4][4];
#pragma unroll
    for (int j = 0; j < 4; ++j) {
      float rs = 0.f;
#pragma unroll
      for (int nf = 0; nf < 4; ++nf) {
        float e = exp2_fast(s[nf][j] - m_r[j]);
        p[nf][j] = e;
        rs += e;
      }
      rs += __shfl_xor(rs, 1);
      rs += __shfl_xor(rs, 2);
      rs += __shfl_xor(rs, 4);
      rs += __shfl_xor(rs, 8);
      l_r[j] += rs;
    }

    // P -> LDS (per-wave region), re-read in A-fragment layout
#pragma unroll
    for (int j = 0; j < 4; ++j)
#pragma unroll
      for (int nf = 0; nf < 4; ++nf)
        Ps[w][lg * 4 + j][nf * 16 + lr] = (_Float16)p[nf][j];

    half8 ap0 = *(const half8*)&Ps[w][lr][lg * 8];
    half8 ap1 = *(const half8*)&Ps[w][lr][32 + lg * 8];
#pragma unroll
    for (int nf = 0; nf < 4; ++nf) {
      int vrow = nf * 16 + lr;
      const char* vb = (const char*)&Vs[0][0] + vrow * 128;
      int sw = (vrow & 7) << 4;
      half8 bv0 = *(const half8*)(vb + ((lg * 16) ^ sw));
      half8 bv1 = *(const half8*)(vb + ((64 + lg * 16) ^ sw));
      accO[nf] = __builtin_amdgcn_mfma_f32_16x16x32_f16(ap0, bv0, accO[nf], 0, 0, 0);
      accO[nf] = __builtin_amdgcn_mfma_f32_16x16x32_f16(ap1, bv1, accO[nf], 0, 0, 0);
    }
  }

#pragma unroll
  for (int j = 0; j < 4; ++j) {
    int tt = q0 + w * 16 + lg * 4 + j;
    if (tt < SEQ) {
      float inv = 1.f / l_r[j];
      _Float16* op = o + (size_t)(b * SEQ + tt) * EMB + h * HDM;
#pragma unroll
      for (int nf = 0; nf < 4; ++nf)
        op[nf * 16 + lr] = (_Float16)(accO[nf][j] * inv);
    }
  }
}

// ---------------- launcher ----------------

extern "C" void kernel_launch(void* const* d_in, const int* in_sizes, int n_in,
                              void* d_out, int out_size, void* d_ws, size_t ws_size,
                              hipStream_t stream) {
  const float* X = (const float*)d_in[0];
  const float* Wq = (const float*)d_in[1];
  const float* bq = (const float*)d_in[2];
  const float* Wk = (const float*)d_in[3];
  const float* Wv = (const float*)d_in[4];
  const float* bv = (const float*)d_in[5];
  const float* Wo = (const float*)d_in[6];
  const float* bo = (const float*)d_in[7];
  float* out = (float*)d_out;

  // workspace layout (all f16): Xh | Wh[4] | qh | kh | vth | aoh  = ~87.5 MB
  _Float16* Xh = (_Float16*)d_ws;
  _Float16* Wh = Xh + (size_t)MPAD * EMB;
  _Float16* qh = Wh + (size_t)4 * WSZ;
  _Float16* kh = qh + (size_t)MPAD * EMB;
  _Float16* vth = kh + (size_t)MPAD * EMB;  // 4*EMB*TPAD == MPAD*EMB
  _Float16* aoh = vth + (size_t)MPAD * EMB;

  cvt_kernel<<<dim3((MTOT * EMB / 8 + 255) / 256), 256, 0, stream>>>(X, Xh,
                                                                     MTOT * EMB / 8);
  cvt4_kernel<<<dim3(WSZ / 8 / 256, 4), 256, 0, stream>>>(Wq, Wk, Wv, Wo, Wh);

  // fused QKV projection: grid.z selects {q,k,v}
  gemm_kernel<<<dim3(10, 48, 3), 256, 0, stream>>>(Xh, Wh, bq, bv, bo, qh, kh, vth,
                                                   out, 0);
  attn_kernel<<<dim3(24, 80), 256, 0, stream>>>(qh, kh, vth, aoh);
  // output projection
  gemm_kernel<<<dim3(10, 48, 1), 256, 0, stream>>>(aoh, Wh + (size_t)3 * WSZ, bq, bv,
                                                   bo, qh, kh, vth, out, 3);
}

// Round 13
// 366.712 us; speedup vs baseline: 1.1620x; 1.1057x over previous
//
#include <hip/hip_runtime.h>

typedef _Float16 half8 __attribute__((ext_vector_type(8)));
typedef _Float16 half4v __attribute__((ext_vector_type(4)));
typedef float f32x4 __attribute__((ext_vector_type(4)));

#define EMB 1280
#define NHD 20
#define HDM 64
#define SEQ 1500
#define MTOT 6000
#define MPAD 6144
#define TPAD 1536
#define WSZ (1280 * 1280)
// 0.125 (head-dim scaling) * log2(e): attention runs in exp2 domain
#define QSCALE 0.18033688011112042f

__device__ __forceinline__ void gload_lds16(const void* g, void* l) {
  __builtin_amdgcn_global_load_lds(
      (const __attribute__((address_space(1))) void*)g,
      (__attribute__((address_space(3))) void*)l, 16, 0, 0);
}

// native v_exp_f32 (exp2). libm exp2f w/o fast-math expands to ~10-inst
// range-handling sequence (r11 regression: VALUBusy 48.5->54.5).
__device__ __forceinline__ float exp2_fast(float x) {
  return __builtin_amdgcn_exp2f(x);
}

// ---------------- f32 -> f16 converts ----------------

__global__ __launch_bounds__(256) void cvt_kernel(const float* __restrict__ s,
                                                  _Float16* __restrict__ d, int n8) {
  int i = blockIdx.x * 256 + threadIdx.x;
  if (i >= n8) return;
  const float4* sp = (const float4*)s + (size_t)i * 2;
  float4 a = sp[0], b = sp[1];
  half8 h;
  h[0] = (_Float16)a.x; h[1] = (_Float16)a.y; h[2] = (_Float16)a.z; h[3] = (_Float16)a.w;
  h[4] = (_Float16)b.x; h[5] = (_Float16)b.y; h[6] = (_Float16)b.z; h[7] = (_Float16)b.w;
  *((half8*)d + i) = h;
}

__global__ __launch_bounds__(256) void cvt4_kernel(const float* __restrict__ w0,
                                                   const float* __restrict__ w1,
                                                   const float* __restrict__ w2,
                                                   const float* __restrict__ w3,
                                                   _Float16* __restrict__ d) {
  const float* srcs[4] = {w0, w1, w2, w3};
  const float* s = srcs[blockIdx.y];
  int i = blockIdx.x * 256 + threadIdx.x;  // < WSZ/8
  const float4* sp = (const float4*)s + (size_t)i * 2;
  float4 a = sp[0], b = sp[1];
  half8 h;
  h[0] = (_Float16)a.x; h[1] = (_Float16)a.y; h[2] = (_Float16)a.z; h[3] = (_Float16)a.w;
  h[4] = (_Float16)b.x; h[5] = (_Float16)b.y; h[6] = (_Float16)b.z; h[7] = (_Float16)b.w;
  *((half8*)d + (size_t)blockIdx.y * (WSZ / 8) + i) = h;
}

// ---------------- GEMM: out[m][n] = sum_k A[m][k] * W[n][k]  (both K-major) ----
// mode 0: q = (acc+bq)*QSCALE -> f16 [MPAD][EMB]   (exp2-domain fold)
// mode 1: k = acc             -> f16 [MPAD][EMB]
// mode 2: v = acc+bv          -> f16 transposed [4][EMB][TPAD]
// mode 3: out = acc+bo        -> f32 [6000][EMB] (guarded)

__global__ __launch_bounds__(256) void gemm_kernel(
    const _Float16* __restrict__ A, const _Float16* __restrict__ Wb,
    const float* __restrict__ bq, const float* __restrict__ bv,
    const float* __restrict__ bo, _Float16* __restrict__ qh,
    _Float16* __restrict__ kh, _Float16* __restrict__ vth,
    float* __restrict__ fout, int mode_base) {
  __shared__ _Float16 As[2][128][32];
  __shared__ _Float16 Bs[2][128][32];
  const int tid = threadIdx.x;
  const int w = tid >> 6, l = tid & 63, lr = l & 15, lg = l >> 4;
  const int wr = w >> 1, wc = w & 1;
  const int rowBase = blockIdx.y * 128;
  const int colBase = blockIdx.x * 128;
  const int mode = mode_base + blockIdx.z;
  const _Float16* Bt = Wb + (size_t)blockIdx.z * WSZ;

  f32x4 acc[4][4] = {};
  const int K = EMB, NT = EMB / 32;

  auto stage = [&](int buf, int t0) {
    const int k0 = t0 * 32;
#pragma unroll
    for (int i = 0; i < 2; ++i) {
      int e = tid * 8 + i * 2048;
      int r = e >> 5, c = e & 31;
      gload_lds16(A + (size_t)(rowBase + r) * K + k0 + c, &As[buf][r][c]);
      gload_lds16(Bt + (size_t)(colBase + r) * K + k0 + c, &Bs[buf][r][c]);
    }
  };

  stage(0, 0);
  __syncthreads();
  int cur = 0;
  for (int t = 0; t < NT; ++t) {
    if (t + 1 < NT) stage(cur ^ 1, t + 1);
    half8 aF[4], bF[4];
#pragma unroll
    for (int mi = 0; mi < 4; ++mi)
      aF[mi] = *(const half8*)&As[cur][wr * 64 + mi * 16 + lr][lg * 8];
#pragma unroll
    for (int ni = 0; ni < 4; ++ni)
      bF[ni] = *(const half8*)&Bs[cur][wc * 64 + ni * 16 + lr][lg * 8];
#pragma unroll
    for (int mi = 0; mi < 4; ++mi)
#pragma unroll
      for (int ni = 0; ni < 4; ++ni)
        acc[mi][ni] = __builtin_amdgcn_mfma_f32_16x16x32_f16(aF[mi], bF[ni],
                                                             acc[mi][ni], 0, 0, 0);
    __syncthreads();
    cur ^= 1;
  }

#pragma unroll
  for (int ni = 0; ni < 4; ++ni) {
    const int col = colBase + wc * 64 + ni * 16 + lr;
    float bias = 0.f;
    if (mode == 0) bias = bq[col];
    else if (mode == 2) bias = bv[col];
    else if (mode == 3) bias = bo[col];
#pragma unroll
    for (int mi = 0; mi < 4; ++mi) {
      const int row0 = rowBase + wr * 64 + mi * 16 + lg * 4;
      if (mode == 0) {
#pragma unroll
        for (int j = 0; j < 4; ++j)
          qh[(size_t)(row0 + j) * EMB + col] =
              (_Float16)((acc[mi][ni][j] + bias) * QSCALE);
      } else if (mode == 1) {
#pragma unroll
        for (int j = 0; j < 4; ++j)
          kh[(size_t)(row0 + j) * EMB + col] = (_Float16)acc[mi][ni][j];
      } else if (mode == 2) {
        if (row0 < MTOT) {  // 4-row group never straddles batch (1500 % 4 == 0)
          int b = row0 / SEQ;
          int tt = row0 - b * SEQ;
          half4v hv;
          hv[0] = (_Float16)(acc[mi][ni][0] + bias);
          hv[1] = (_Float16)(acc[mi][ni][1] + bias);
          hv[2] = (_Float16)(acc[mi][ni][2] + bias);
          hv[3] = (_Float16)(acc[mi][ni][3] + bias);
          *(half4v*)(vth + ((size_t)b * EMB + col) * TPAD + tt) = hv;
        }
      } else {
#pragma unroll
        for (int j = 0; j < 4; ++j)
          if (row0 + j < MTOT)
            fout[(size_t)(row0 + j) * EMB + col] = acc[mi][ni][j] + bias;
      }
    }
  }
}

// ---------------- flash attention ----------------
// rev5: 8 waves / 128 q-rows per block (grid 12x80=960, all co-resident at
// 4 blocks/CU = 32 waves/CU). K/V staged once per 128 q-rows (2x amortization
// of stage+barrier vs rev4); row-sum l computed by ones-MFMA (deletes the
// 16-shuffle rs reduce; numerator & denominator share the f16-quantized P).
// Keeps: single-buffer K/V, XOR swizzle, native exp2, defer-max THR=8.

__global__ __launch_bounds__(512) void attn_kernel(const _Float16* __restrict__ q,
                                                   const _Float16* __restrict__ k,
                                                   const _Float16* __restrict__ vt,
                                                   _Float16* __restrict__ o) {
  __shared__ _Float16 Ks[64][64];
  __shared__ _Float16 Vs[64][64];
  __shared__ _Float16 Ps[8][16][72];  // +8 pad: breaks conflicts on P reads

  const int qt = blockIdx.x;
  const int bh = blockIdx.y;
  const int b = bh / NHD, h = bh % NHD;
  const int tid = threadIdx.x;
  const int w = tid >> 6, l = tid & 63, lr = l & 15, lg = l >> 4;

  const int q0 = qt * 128;
  const int qrow = q0 + w * 16 + lr;  // may exceed SEQ: stays within MPAD, not stored
  const _Float16* qp = q + (size_t)(b * SEQ + qrow) * EMB + h * HDM;
  half8 aq0 = *(const half8*)(qp + lg * 8);
  half8 aq1 = *(const half8*)(qp + 32 + lg * 8);

  half8 ones;
#pragma unroll
  for (int i = 0; i < 8; ++i) ones[i] = (_Float16)1.0f;

  float m_r[4];
  f32x4 accL;  // accL[j] = running sum of P over kv for q-row lg*4+j (ones-MFMA)
  f32x4 accO[4];
#pragma unroll
  for (int j = 0; j < 4; ++j) m_r[j] = -1e30f;
  accL[0] = 0.f; accL[1] = 0.f; accL[2] = 0.f; accL[3] = 0.f;
#pragma unroll
  for (int nf = 0; nf < 4; ++nf) {
    accO[nf][0] = 0.f; accO[nf][1] = 0.f; accO[nf][2] = 0.f; accO[nf][3] = 0.f;
  }

  const char* kBase = (const char*)(k + (size_t)b * SEQ * EMB + h * HDM);
  const char* vBase = (const char*)(vt + ((size_t)b * EMB + h * HDM) * TPAD);

  for (int kt = 0; kt < 24; ++kt) {
    const int kv0 = kt * 64;
    __syncthreads();  // prev tile's LDS reads complete before overwrite
    {
      // 512 threads x 16B = 8KB: one K load + one V load per thread
      int o4 = tid * 16;
      int r = o4 >> 7;
      int inner = o4 & 127;
      int srcoff = inner ^ ((r & 7) << 4);
      gload_lds16(kBase + (size_t)(kv0 + r) * (EMB * 2) + srcoff,
                  (char*)&Ks[0][0] + o4);
      gload_lds16(vBase + (size_t)r * (TPAD * 2) + (size_t)kv0 * 2 + srcoff,
                  (char*)&Vs[0][0] + o4);
    }
    __syncthreads();  // drains vmcnt (compiler emits vmcnt(0) before s_barrier)

    // S = Q K^T  (C-layout: q-row = lg*4+j; kv col = nf*16+lr), log2 domain
    f32x4 s[4];
#pragma unroll
    for (int nf = 0; nf < 4; ++nf) {
      int krow = nf * 16 + lr;
      const char* kb = (const char*)&Ks[0][0] + krow * 128;
      int sw = (krow & 7) << 4;
      half8 bk0 = *(const half8*)(kb + ((lg * 16) ^ sw));
      half8 bk1 = *(const half8*)(kb + ((64 + lg * 16) ^ sw));
      f32x4 t = {0.f, 0.f, 0.f, 0.f};
      t = __builtin_amdgcn_mfma_f32_16x16x32_f16(aq0, bk0, t, 0, 0, 0);
      t = __builtin_amdgcn_mfma_f32_16x16x32_f16(aq1, bk1, t, 0, 0, 0);
      if (kv0 + krow >= SEQ) { t[0] = -1e30f; t[1] = -1e30f; t[2] = -1e30f; t[3] = -1e30f; }
      s[nf] = t;
    }

    // tile row-max (reduce across the 16-lane lr group)
    float pmax[4];
#pragma unroll
    for (int j = 0; j < 4; ++j) {
      float mx = fmaxf(fmaxf(s[0][j], s[1][j]), fmaxf(s[2][j], s[3][j]));
      mx = fmaxf(mx, __shfl_xor(mx, 1));
      mx = fmaxf(mx, __shfl_xor(mx, 2));
      mx = fmaxf(mx, __shfl_xor(mx, 4));
      mx = fmaxf(mx, __shfl_xor(mx, 8));
      pmax[j] = mx;
    }
    // defer-max: skip O/l rescale while max growth < 8 (P bounded by 2^8, f16-safe)
    float dm = fmaxf(fmaxf(pmax[0] - m_r[0], pmax[1] - m_r[1]),
                     fmaxf(pmax[2] - m_r[2], pmax[3] - m_r[3]));
    if (!__all(dm <= 8.0f)) {
#pragma unroll
      for (int j = 0; j < 4; ++j) {
        float mnew = fmaxf(m_r[j], pmax[j]);
        float corr = exp2_fast(m_r[j] - mnew);
        m_r[j] = mnew;
        accL[j] *= corr;
#pragma unroll
        for (int nf = 0; nf < 4; ++nf) accO[nf][j] *= corr;
      }
    }

    // P = exp2(S - m); -> LDS (per-wave region), re-read in A-fragment layout
#pragma unroll
    for (int j = 0; j < 4; ++j)
#pragma unroll
      for (int nf = 0; nf < 4; ++nf)
        Ps[w][lg * 4 + j][nf * 16 + lr] = (_Float16)exp2_fast(s[nf][j] - m_r[j]);

    half8 ap0 = *(const half8*)&Ps[w][lr][lg * 8];
    half8 ap1 = *(const half8*)&Ps[w][lr][32 + lg * 8];
    // row-sum via ones-MFMA: every D column gets sum_kv P[row][kv]
    accL = __builtin_amdgcn_mfma_f32_16x16x32_f16(ap0, ones, accL, 0, 0, 0);
    accL = __builtin_amdgcn_mfma_f32_16x16x32_f16(ap1, ones, accL, 0, 0, 0);
#pragma unroll
    for (int nf = 0; nf < 4; ++nf) {
      int vrow = nf * 16 + lr;
      const char* vb = (const char*)&Vs[0][0] + vrow * 128;
      int sw = (vrow & 7) << 4;
      half8 bv0 = *(const half8*)(vb + ((lg * 16) ^ sw));
      half8 bv1 = *(const half8*)(vb + ((64 + lg * 16) ^ sw));
      accO[nf] = __builtin_amdgcn_mfma_f32_16x16x32_f16(ap0, bv0, accO[nf], 0, 0, 0);
      accO[nf] = __builtin_amdgcn_mfma_f32_16x16x32_f16(ap1, bv1, accO[nf], 0, 0, 0);
    }
  }

#pragma unroll
  for (int j = 0; j < 4; ++j) {
    int tt = q0 + w * 16 + lg * 4 + j;
    if (tt < SEQ) {
      float inv = 1.f / accL[j];
      _Float16* op = o + (size_t)(b * SEQ + tt) * EMB + h * HDM;
#pragma unroll
      for (int nf = 0; nf < 4; ++nf)
        op[nf * 16 + lr] = (_Float16)(accO[nf][j] * inv);
    }
  }
}

// ---------------- launcher ----------------

extern "C" void kernel_launch(void* const* d_in, const int* in_sizes, int n_in,
                              void* d_out, int out_size, void* d_ws, size_t ws_size,
                              hipStream_t stream) {
  const float* X = (const float*)d_in[0];
  const float* Wq = (const float*)d_in[1];
  const float* bq = (const float*)d_in[2];
  const float* Wk = (const float*)d_in[3];
  const float* Wv = (const float*)d_in[4];
  const float* bv = (const float*)d_in[5];
  const float* Wo = (const float*)d_in[6];
  const float* bo = (const float*)d_in[7];
  float* out = (float*)d_out;

  // workspace layout (all f16): Xh | Wh[4] | qh | kh | vth | aoh  = ~87.5 MB
  _Float16* Xh = (_Float16*)d_ws;
  _Float16* Wh = Xh + (size_t)MPAD * EMB;
  _Float16* qh = Wh + (size_t)4 * WSZ;
  _Float16* kh = qh + (size_t)MPAD * EMB;
  _Float16* vth = kh + (size_t)MPAD * EMB;  // 4*EMB*TPAD == MPAD*EMB
  _Float16* aoh = vth + (size_t)MPAD * EMB;

  cvt_kernel<<<dim3((MTOT * EMB / 8 + 255) / 256), 256, 0, stream>>>(X, Xh,
                                                                     MTOT * EMB / 8);
  cvt4_kernel<<<dim3(WSZ / 8 / 256, 4), 256, 0, stream>>>(Wq, Wk, Wv, Wo, Wh);

  // fused QKV projection: grid.z selects {q,k,v}
  gemm_kernel<<<dim3(10, 48, 3), 256, 0, stream>>>(Xh, Wh, bq, bv, bo, qh, kh, vth,
                                                   out, 0);
  attn_kernel<<<dim3(12, 80), 512, 0, stream>>>(qh, kh, vth, aoh);
  // output projection
  gemm_kernel<<<dim3(10, 48, 1), 256, 0, stream>>>(aoh, Wh + (size_t)3 * WSZ, bq, bv,
                                                   bo, qh, kh, vth, out, 3);
}